// Round 13
// baseline (325.929 us; speedup 1.0000x reference)
//
#include <hip/hip_runtime.h>

#define Q_INV (1.0f / 128.0f)

__device__ __forceinline__ float quant_comp_f(float v) {
    float f = floorf(v * 128.0f);
    f = fminf(fmaxf(f, -128.0f), 127.0f);
    int qi = (int)f;
    qi |= 1;
    return (float)qi * Q_INV;
}

__device__ __forceinline__ float getf(const float4 v, const int c) {
    return c == 0 ? v.x : (c == 1 ? v.y : (c == 2 ? v.z : v.w));
}

// R9/R11 conv structure; change vs R12: conv2 weights staged TRANSPOSED+PADDED
// (w2t[c*160 + ky*32 + ic*5 + kx]) and preloaded into registers per (c,ky) as
// 8 float4 reads, replacing 150 per-lane ds_read_b32 + addressing in the inner
// loop. FMA chain order (ky,kx,ic) unchanged -> bit-identical results.
__global__ __launch_bounds__(192) void conv_fused_kernel(
    const float* __restrict__ x,
    const float* __restrict__ c1w, const float* __restrict__ c1b,
    const float* __restrict__ c2w, const float* __restrict__ c2b,
    const int* __restrict__ qflag,
    float* __restrict__ act)
{
    // arena: phase A: pin[32][36] (1152) ; phase B: rowmax1[6][28][17] (2856)
    //        phase C: w2t[2560] + rowmax2[1280] at +2560 -> 3840 total
    __shared__ __align__(16) float shpool[3840];
    __shared__ float w1s[150];
    __shared__ float b1s[6];
    __shared__ float b2s[16];
    __shared__ __align__(16) float mid[6][14][20];

    float (*pin)[36] = reinterpret_cast<float(*)[36]>(shpool);

    const int t = threadIdx.x;
    const int img = blockIdx.x;
    const bool q = (qflag[0] != 0);

    for (int i = t; i < 1152; i += 192) shpool[i] = 0.0f;
    if (t < 150) w1s[t] = c1w[t];
    if (t < 6) b1s[t] = c1b[t];
    if (t < 16) b2s[t] = c2b[t];
    __syncthreads();

    const float* xi = x + (size_t)img * 784;
    for (int i = t; i < 784; i += 192) {
        float v = xi[i];
        if (q) v = quant_comp_f(v);
        pin[i / 28 + 2][i % 28 + 2] = v;
    }
    __syncthreads();

    // ---- conv1 (unchanged from R11) ----
    float hmax1[14];
    if (t < 168) {
        const int c = t / 28, oh = t % 28;
        float acc[28];
        #pragma unroll
        for (int j = 0; j < 28; ++j) acc[j] = 0.0f;
        #pragma unroll
        for (int ky = 0; ky < 5; ++ky) {
            const float4* pr = reinterpret_cast<const float4*>(&pin[oh + ky][0]);
            float4 r4[8];
            #pragma unroll
            for (int j = 0; j < 8; ++j) r4[j] = pr[j];
            #pragma unroll
            for (int kx = 0; kx < 5; ++kx) {
                const float wv = w1s[c * 25 + ky * 5 + kx];
                #pragma unroll
                for (int ow = 0; ow < 28; ++ow) {
                    const int idx = ow + kx;
                    acc[ow] = fmaf(getf(r4[idx >> 2], idx & 3), wv, acc[ow]);
                }
            }
        }
        const float bb = b1s[c];
        #pragma unroll
        for (int j = 0; j < 14; ++j) {
            float v0 = acc[2*j] + bb;
            float v1 = acc[2*j + 1] + bb;
            hmax1[j] = fmaxf(v0, v1);
        }
    }
    __syncthreads();
    if (t < 168) {
        const int c = t / 28, oh = t % 28;
        #pragma unroll
        for (int j = 0; j < 14; ++j) shpool[(c * 28 + oh) * 17 + j] = hmax1[j];
    }
    __syncthreads();
    if (t < 84) {
        const int c = t / 14, ph = t % 14;
        #pragma unroll
        for (int j = 0; j < 14; ++j) {
            float m = fmaxf(shpool[(c * 28 + 2 * ph) * 17 + j],
                            shpool[(c * 28 + 2 * ph + 1) * 17 + j]);
            m = fmaxf(m, 0.0f);
            if (q) m = quant_comp_f(m);
            mid[c][ph][j] = m;
        }
    }
    __syncthreads();   // rowmax1 dead; arena head becomes w2t[2560]

    // stage w2 transposed+padded: w2t[c*160 + ky*32 + ic*5 + kx]
    for (int i = t; i < 2560; i += 192) {
        const int c = i / 160;
        const int r = i % 160;
        const int ky = r / 32;
        const int s = r % 32;
        float v = 0.0f;
        if (s < 30) {
            const int ic = s / 5, kx = s % 5;
            v = c2w[(c * 6 + ic) * 25 + ky * 5 + kx];
        }
        shpool[i] = v;
    }
    __syncthreads();

    const float* w2t = shpool;
    float* rowmax2 = shpool + 2560;

    // ---- conv2: per (c,ky) weights preloaded to registers via 8 float4 ----
    float hmax2[5];
    if (t < 160) {
        const int c = t / 10, oh = t % 10;
        float acc[10];
        #pragma unroll
        for (int j = 0; j < 10; ++j) acc[j] = 0.0f;
        #pragma unroll
        for (int ky = 0; ky < 5; ++ky) {
            float4 rb4[6][4];
            #pragma unroll
            for (int ic = 0; ic < 6; ++ic) {
                const float4* mr = reinterpret_cast<const float4*>(&mid[ic][oh + ky][0]);
                #pragma unroll
                for (int j2 = 0; j2 < 4; ++j2) rb4[ic][j2] = mr[j2];
            }
            float4 wk4[8];
            {
                const float4* wp = reinterpret_cast<const float4*>(&w2t[c * 160 + ky * 32]);
                #pragma unroll
                for (int j2 = 0; j2 < 8; ++j2) wk4[j2] = wp[j2];
            }
            #pragma unroll
            for (int kx = 0; kx < 5; ++kx) {
                #pragma unroll
                for (int ic = 0; ic < 6; ++ic) {
                    const int wi = ic * 5 + kx;
                    const float wv = getf(wk4[wi >> 2], wi & 3);
                    #pragma unroll
                    for (int ow = 0; ow < 10; ++ow) {
                        const int idx = ow + kx;
                        acc[ow] = fmaf(getf(rb4[ic][idx >> 2], idx & 3), wv, acc[ow]);
                    }
                }
            }
        }
        const float bb = b2s[c];
        #pragma unroll
        for (int j = 0; j < 5; ++j) {
            float v0 = acc[2*j] + bb;
            float v1 = acc[2*j + 1] + bb;
            hmax2[j] = fmaxf(v0, v1);
        }
    }
    if (t < 160) {
        const int c = t / 10, oh = t % 10;
        #pragma unroll
        for (int j = 0; j < 5; ++j) rowmax2[(c * 10 + oh) * 8 + j] = hmax2[j];
    }
    __syncthreads();
    if (t < 80) {
        const int c = t / 5, ph = t % 5;
        float* ao = act + (size_t)img * 400;
        #pragma unroll
        for (int j = 0; j < 5; ++j) {
            float m = fmaxf(rowmax2[(c * 10 + 2 * ph) * 8 + j],
                            rowmax2[(c * 10 + 2 * ph + 1) * 8 + j]);
            m = fmaxf(m, 0.0f);
            if (q) m = quant_comp_f(m);
            ao[c * 25 + ph * 5 + j] = m;
        }
    }
}

// R12 fc kernel verbatim (verified: ~37 µs).
__global__ __launch_bounds__(256) void fc_fused_kernel(
    const float* __restrict__ act,
    const float* __restrict__ w1, const float* __restrict__ b1,
    const float* __restrict__ w2, const float* __restrict__ b2,
    const float* __restrict__ w3, const float* __restrict__ b3,
    const int* __restrict__ qflag,
    float* __restrict__ out, int B)
{
    __shared__ __align__(16) float wt[120][44];
    __shared__ __align__(16) float a0c[16][44];
    __shared__ __align__(16) float a1[16][124];
    __shared__ __align__(16) float a2[16][88];

    const int t = threadIdx.x;
    const bool q = (qflag[0] != 0);
    const int base = blockIdx.x * 16;
    const int og = t >> 3;
    const int ig = t & 7;

    float acc[4][2];
    #pragma unroll
    for (int j = 0; j < 4; ++j) { acc[j][0] = 0.0f; acc[j][1] = 0.0f; }

    for (int ch = 0; ch < 10; ++ch) {
        __syncthreads();
        for (int i = t; i < 1200; i += 256) {
            const int slot = i / 10, s = i % 10;
            const int orig = ((slot % 30) << 2) + (slot / 30);
            *reinterpret_cast<float4*>(&wt[slot][s * 4]) =
                *reinterpret_cast<const float4*>(w1 + orig * 400 + ch * 40 + s * 4);
        }
        for (int i = t; i < 160; i += 256) {
            const int imm = i / 10, s = i % 10;
            if (base + imm < B)
                *reinterpret_cast<float4*>(&a0c[imm][s * 4]) =
                    *reinterpret_cast<const float4*>(act + (size_t)(base + imm) * 400 + ch * 40 + s * 4);
        }
        __syncthreads();
        if (og < 30) {
            #pragma unroll
            for (int kk = 0; kk < 10; ++kk) {
                const float4 av0 = *reinterpret_cast<const float4*>(&a0c[2*ig][kk*4]);
                const float4 av1 = *reinterpret_cast<const float4*>(&a0c[2*ig+1][kk*4]);
                const float4 w0 = *reinterpret_cast<const float4*>(&wt[og][kk*4]);
                const float4 wv1 = *reinterpret_cast<const float4*>(&wt[30+og][kk*4]);
                const float4 wv2 = *reinterpret_cast<const float4*>(&wt[60+og][kk*4]);
                const float4 wv3 = *reinterpret_cast<const float4*>(&wt[90+og][kk*4]);
                acc[0][0]=fmaf(av0.x,w0.x,acc[0][0]);  acc[0][1]=fmaf(av1.x,w0.x,acc[0][1]);
                acc[1][0]=fmaf(av0.x,wv1.x,acc[1][0]); acc[1][1]=fmaf(av1.x,wv1.x,acc[1][1]);
                acc[2][0]=fmaf(av0.x,wv2.x,acc[2][0]); acc[2][1]=fmaf(av1.x,wv2.x,acc[2][1]);
                acc[3][0]=fmaf(av0.x,wv3.x,acc[3][0]); acc[3][1]=fmaf(av1.x,wv3.x,acc[3][1]);
                acc[0][0]=fmaf(av0.y,w0.y,acc[0][0]);  acc[0][1]=fmaf(av1.y,w0.y,acc[0][1]);
                acc[1][0]=fmaf(av0.y,wv1.y,acc[1][0]); acc[1][1]=fmaf(av1.y,wv1.y,acc[1][1]);
                acc[2][0]=fmaf(av0.y,wv2.y,acc[2][0]); acc[2][1]=fmaf(av1.y,wv2.y,acc[2][1]);
                acc[3][0]=fmaf(av0.y,wv3.y,acc[3][0]); acc[3][1]=fmaf(av1.y,wv3.y,acc[3][1]);
                acc[0][0]=fmaf(av0.z,w0.z,acc[0][0]);  acc[0][1]=fmaf(av1.z,w0.z,acc[0][1]);
                acc[1][0]=fmaf(av0.z,wv1.z,acc[1][0]); acc[1][1]=fmaf(av1.z,wv1.z,acc[1][1]);
                acc[2][0]=fmaf(av0.z,wv2.z,acc[2][0]); acc[2][1]=fmaf(av1.z,wv2.z,acc[2][1]);
                acc[3][0]=fmaf(av0.z,wv3.z,acc[3][0]); acc[3][1]=fmaf(av1.z,wv3.z,acc[3][1]);
                acc[0][0]=fmaf(av0.w,w0.w,acc[0][0]);  acc[0][1]=fmaf(av1.w,w0.w,acc[0][1]);
                acc[1][0]=fmaf(av0.w,wv1.w,acc[1][0]); acc[1][1]=fmaf(av1.w,wv1.w,acc[1][1]);
                acc[2][0]=fmaf(av0.w,wv2.w,acc[2][0]); acc[2][1]=fmaf(av1.w,wv2.w,acc[2][1]);
                acc[3][0]=fmaf(av0.w,wv3.w,acc[3][0]); acc[3][1]=fmaf(av1.w,wv3.w,acc[3][1]);
            }
        }
    }
    if (og < 30) {
        #pragma unroll
        for (int j = 0; j < 4; ++j) {
            const int o = og * 4 + j;
            #pragma unroll
            for (int i = 0; i < 2; ++i) {
                float v = acc[j][i] + b1[o];
                v = fmaxf(v, 0.0f);
                a1[2*ig + i][o] = q ? quant_comp_f(v) : v;
            }
        }
    }

    float bcc[4][2];
    #pragma unroll
    for (int j = 0; j < 4; ++j) { bcc[j][0] = 0.0f; bcc[j][1] = 0.0f; }

    for (int ch = 0; ch < 3; ++ch) {
        __syncthreads();
        for (int i = t; i < 840; i += 256) {
            const int slot = i / 10, s = i % 10;
            const int orig = ((slot % 21) << 2) + (slot / 21);
            *reinterpret_cast<float4*>(&wt[slot][s * 4]) =
                *reinterpret_cast<const float4*>(w2 + orig * 120 + ch * 40 + s * 4);
        }
        __syncthreads();
        if (og < 21) {
            #pragma unroll
            for (int kk = 0; kk < 10; ++kk) {
                const float4 av0 = *reinterpret_cast<const float4*>(&a1[2*ig][ch*40 + kk*4]);
                const float4 av1 = *reinterpret_cast<const float4*>(&a1[2*ig+1][ch*40 + kk*4]);
                const float4 w0 = *reinterpret_cast<const float4*>(&wt[og][kk*4]);
                const float4 wv1 = *reinterpret_cast<const float4*>(&wt[21+og][kk*4]);
                const float4 wv2 = *reinterpret_cast<const float4*>(&wt[42+og][kk*4]);
                const float4 wv3 = *reinterpret_cast<const float4*>(&wt[63+og][kk*4]);
                bcc[0][0]=fmaf(av0.x,w0.x,bcc[0][0]);  bcc[0][1]=fmaf(av1.x,w0.x,bcc[0][1]);
                bcc[1][0]=fmaf(av0.x,wv1.x,bcc[1][0]); bcc[1][1]=fmaf(av1.x,wv1.x,bcc[1][1]);
                bcc[2][0]=fmaf(av0.x,wv2.x,bcc[2][0]); bcc[2][1]=fmaf(av1.x,wv2.x,bcc[2][1]);
                bcc[3][0]=fmaf(av0.x,wv3.x,bcc[3][0]); bcc[3][1]=fmaf(av1.x,wv3.x,bcc[3][1]);
                bcc[0][0]=fmaf(av0.y,w0.y,bcc[0][0]);  bcc[0][1]=fmaf(av1.y,w0.y,bcc[0][1]);
                bcc[1][0]=fmaf(av0.y,wv1.y,bcc[1][0]); bcc[1][1]=fmaf(av1.y,wv1.y,bcc[1][1]);
                bcc[2][0]=fmaf(av0.y,wv2.y,bcc[2][0]); bcc[2][1]=fmaf(av1.y,wv2.y,bcc[2][1]);
                bcc[3][0]=fmaf(av0.y,wv3.y,bcc[3][0]); bcc[3][1]=fmaf(av1.y,wv3.y,bcc[3][1]);
                bcc[0][0]=fmaf(av0.z,w0.z,bcc[0][0]);  bcc[0][1]=fmaf(av1.z,w0.z,bcc[0][1]);
                bcc[1][0]=fmaf(av0.z,wv1.z,bcc[1][0]); bcc[1][1]=fmaf(av1.z,wv1.z,bcc[1][1]);
                bcc[2][0]=fmaf(av0.z,wv2.z,bcc[2][0]); bcc[2][1]=fmaf(av1.z,wv2.z,bcc[2][1]);
                bcc[3][0]=fmaf(av0.z,wv3.z,bcc[3][0]); bcc[3][1]=fmaf(av1.z,wv3.z,bcc[3][1]);
                bcc[0][0]=fmaf(av0.w,w0.w,bcc[0][0]);  bcc[0][1]=fmaf(av1.w,w0.w,bcc[0][1]);
                bcc[1][0]=fmaf(av0.w,wv1.w,bcc[1][0]); bcc[1][1]=fmaf(av1.w,wv1.w,bcc[1][1]);
                bcc[2][0]=fmaf(av0.w,wv2.w,bcc[2][0]); bcc[2][1]=fmaf(av1.w,wv2.w,bcc[2][1]);
                bcc[3][0]=fmaf(av0.w,wv3.w,bcc[3][0]); bcc[3][1]=fmaf(av1.w,wv3.w,bcc[3][1]);
            }
        }
    }
    if (og < 21) {
        #pragma unroll
        for (int j = 0; j < 4; ++j) {
            const int o = og * 4 + j;
            #pragma unroll
            for (int i = 0; i < 2; ++i) {
                float v = bcc[j][i] + b2[o];
                v = fmaxf(v, 0.0f);
                a2[2*ig + i][o] = q ? quant_comp_f(v) : v;
            }
        }
    }

    __syncthreads();
    {
        float* wtf = &wt[0][0];
        for (int i = t; i < 210; i += 256)
            reinterpret_cast<float4*>(wtf)[i] =
                reinterpret_cast<const float4*>(w3)[i];
    }
    __syncthreads();
    {
        const int grp = t >> 4;
        const int im = t & 15;
        const int o0 = 2 * grp;
        if (o0 < 10) {
            const float* wtf = &wt[0][0];
            float s0 = 0.0f, s1 = 0.0f;
            #pragma unroll
            for (int kk = 0; kk < 21; ++kk) {
                const float4 av = *reinterpret_cast<const float4*>(&a2[im][kk*4]);
                const float4 wa = *reinterpret_cast<const float4*>(&wtf[o0*84 + kk*4]);
                const float4 wb = *reinterpret_cast<const float4*>(&wtf[(o0+1)*84 + kk*4]);
                s0 = fmaf(av.x, wa.x, s0); s1 = fmaf(av.x, wb.x, s1);
                s0 = fmaf(av.y, wa.y, s0); s1 = fmaf(av.y, wb.y, s1);
                s0 = fmaf(av.z, wa.z, s0); s1 = fmaf(av.z, wb.z, s1);
                s0 = fmaf(av.w, wa.w, s0); s1 = fmaf(av.w, wb.w, s1);
            }
            if (base + im < B) {
                out[(size_t)(base + im) * 10 + o0]     = s0 + b3[o0];
                out[(size_t)(base + im) * 10 + o0 + 1] = s1 + b3[o0 + 1];
            }
        }
    }
}

extern "C" void kernel_launch(void* const* d_in, const int* in_sizes, int n_in,
                              void* d_out, int out_size, void* d_ws, size_t ws_size,
                              hipStream_t stream) {
    const float* x     = (const float*)d_in[0];
    const float* c1w   = (const float*)d_in[1];
    const float* c1b   = (const float*)d_in[2];
    const float* c2w   = (const float*)d_in[3];
    const float* c2b   = (const float*)d_in[4];
    const float* fc1w  = (const float*)d_in[5];
    const float* fc1b  = (const float*)d_in[6];
    const float* fc2w  = (const float*)d_in[7];
    const float* fc2b  = (const float*)d_in[8];
    const float* fc3w  = (const float*)d_in[9];
    const float* fc3b  = (const float*)d_in[10];
    const int*   qflag = (const int*)d_in[11];
    float* out = (float*)d_out;

    const int B = in_sizes[0] / 784;
    float* act = (float*)d_ws;  // [B,400]

    conv_fused_kernel<<<B, 192, 0, stream>>>(x, c1w, c1b, c2w, c2b, qflag, act);

    const int nblk = (B + 15) / 16;
    fc_fused_kernel<<<nblk, 256, 0, stream>>>(act, fc1w, fc1b, fc2w, fc2b,
                                              fc3w, fc3b, qflag, out, B);
}

// Round 14
// 293.080 us; speedup vs baseline: 1.1121x; 1.1121x over previous
//
#include <hip/hip_runtime.h>

#define Q_INV (1.0f / 128.0f)

__device__ __forceinline__ float quant_comp_f(float v) {
    float f = floorf(v * 128.0f);
    f = fminf(fmaxf(f, -128.0f), 127.0f);
    int qi = (int)f;
    qi |= 1;
    return (float)qi * Q_INV;
}

__device__ __forceinline__ float getf(const float4 v, const int c) {
    return c == 0 ? v.x : (c == 1 ? v.y : (c == 2 ? v.z : v.w));
}

// R12 conv kernel with ONE change: conv1 lane mapping (c=t%6, oh=t/6) so a
// wave holds 11 distinct pin rows (6 lanes/row broadcast) instead of 28 ->
// pin-read bank conflicts ~3.5-way -> ~1.4-way. Work/chains bit-identical.
__global__ __launch_bounds__(192) void conv_fused_kernel(
    const float* __restrict__ x,
    const float* __restrict__ c1w, const float* __restrict__ c1b,
    const float* __restrict__ c2w, const float* __restrict__ c2b,
    const int* __restrict__ qflag,
    float* __restrict__ act)
{
    // arena: phase A: pin[32][36] (1152) ; phase B: rowmax1[6][28][17] (2856)
    //        phase C: w2s[2400] + rowmax2[1280] at +2400 -> 3680 total
    __shared__ __align__(16) float shpool[3680];
    __shared__ float w1s[150];
    __shared__ float b1s[6];
    __shared__ float b2s[16];
    __shared__ __align__(16) float mid[6][14][20];

    float (*pin)[36] = reinterpret_cast<float(*)[36]>(shpool);

    const int t = threadIdx.x;
    const int img = blockIdx.x;
    const bool q = (qflag[0] != 0);

    for (int i = t; i < 1152; i += 192) shpool[i] = 0.0f;
    if (t < 150) w1s[t] = c1w[t];
    if (t < 6) b1s[t] = c1b[t];
    if (t < 16) b2s[t] = c2b[t];
    __syncthreads();

    const float* xi = x + (size_t)img * 784;
    for (int i = t; i < 784; i += 192) {
        float v = xi[i];
        if (q) v = quant_comp_f(v);
        pin[i / 28 + 2][i % 28 + 2] = v;
    }
    __syncthreads();

    // ---- conv1: t<168, lane map (c=t%6, oh=t/6); 28 outputs in registers ----
    float hmax1[14];
    if (t < 168) {
        const int c = t % 6, oh = t / 6;
        float acc[28];
        #pragma unroll
        for (int j = 0; j < 28; ++j) acc[j] = 0.0f;
        #pragma unroll
        for (int ky = 0; ky < 5; ++ky) {
            const float4* pr = reinterpret_cast<const float4*>(&pin[oh + ky][0]);
            float4 r4[8];
            #pragma unroll
            for (int j = 0; j < 8; ++j) r4[j] = pr[j];
            #pragma unroll
            for (int kx = 0; kx < 5; ++kx) {
                const float wv = w1s[c * 25 + ky * 5 + kx];
                #pragma unroll
                for (int ow = 0; ow < 28; ++ow) {
                    const int idx = ow + kx;
                    acc[ow] = fmaf(getf(r4[idx >> 2], idx & 3), wv, acc[ow]);
                }
            }
        }
        const float bb = b1s[c];
        #pragma unroll
        for (int j = 0; j < 14; ++j) {
            float v0 = acc[2*j] + bb;
            float v1 = acc[2*j + 1] + bb;
            hmax1[j] = fmaxf(v0, v1);
        }
    }
    __syncthreads();
    if (t < 168) {
        const int c = t % 6, oh = t / 6;
        #pragma unroll
        for (int j = 0; j < 14; ++j) shpool[(c * 28 + oh) * 17 + j] = hmax1[j];
    }
    __syncthreads();
    if (t < 84) {
        const int c = t / 14, ph = t % 14;
        #pragma unroll
        for (int j = 0; j < 14; ++j) {
            float m = fmaxf(shpool[(c * 28 + 2 * ph) * 17 + j],
                            shpool[(c * 28 + 2 * ph + 1) * 17 + j]);
            m = fmaxf(m, 0.0f);
            if (q) m = quant_comp_f(m);
            mid[c][ph][j] = m;
        }
    }
    __syncthreads();   // rowmax1 dead; arena head becomes w2s[2400]

    {
        const float4* src = reinterpret_cast<const float4*>(c2w);
        float4* dst = reinterpret_cast<float4*>(shpool);
        for (int i = t; i < 600; i += 192) dst[i] = src[i];
    }
    __syncthreads();

    const float* w2s = shpool;
    float* rowmax2 = shpool + 2400;

    // ---- conv2 (R12 verbatim) ----
    float hmax2[5];
    if (t < 160) {
        const int c = t / 10, oh = t % 10;
        float acc[10];
        #pragma unroll
        for (int j = 0; j < 10; ++j) acc[j] = 0.0f;
        #pragma unroll
        for (int ky = 0; ky < 5; ++ky) {
            float4 rb4[6][4];
            #pragma unroll
            for (int ic = 0; ic < 6; ++ic) {
                const float4* mr = reinterpret_cast<const float4*>(&mid[ic][oh + ky][0]);
                #pragma unroll
                for (int j2 = 0; j2 < 4; ++j2) rb4[ic][j2] = mr[j2];
            }
            #pragma unroll
            for (int kx = 0; kx < 5; ++kx) {
                #pragma unroll
                for (int ic = 0; ic < 6; ++ic) {
                    const float wv = w2s[(c * 6 + ic) * 25 + ky * 5 + kx];
                    #pragma unroll
                    for (int ow = 0; ow < 10; ++ow) {
                        const int idx = ow + kx;
                        acc[ow] = fmaf(getf(rb4[ic][idx >> 2], idx & 3), wv, acc[ow]);
                    }
                }
            }
        }
        const float bb = b2s[c];
        #pragma unroll
        for (int j = 0; j < 5; ++j) {
            float v0 = acc[2*j] + bb;
            float v1 = acc[2*j + 1] + bb;
            hmax2[j] = fmaxf(v0, v1);
        }
    }
    if (t < 160) {
        const int c = t / 10, oh = t % 10;
        #pragma unroll
        for (int j = 0; j < 5; ++j) rowmax2[(c * 10 + oh) * 8 + j] = hmax2[j];
    }
    __syncthreads();
    if (t < 80) {
        const int c = t / 5, ph = t % 5;
        float* ao = act + (size_t)img * 400;
        #pragma unroll
        for (int j = 0; j < 5; ++j) {
            float m = fmaxf(rowmax2[(c * 10 + 2 * ph) * 8 + j],
                            rowmax2[(c * 10 + 2 * ph + 1) * 8 + j]);
            m = fmaxf(m, 0.0f);
            if (q) m = quant_comp_f(m);
            ao[c * 25 + ph * 5 + j] = m;
        }
    }
}

// R12 fc kernel verbatim (verified: ~37 µs).
__global__ __launch_bounds__(256) void fc_fused_kernel(
    const float* __restrict__ act,
    const float* __restrict__ w1, const float* __restrict__ b1,
    const float* __restrict__ w2, const float* __restrict__ b2,
    const float* __restrict__ w3, const float* __restrict__ b3,
    const int* __restrict__ qflag,
    float* __restrict__ out, int B)
{
    __shared__ __align__(16) float wt[120][44];
    __shared__ __align__(16) float a0c[16][44];
    __shared__ __align__(16) float a1[16][124];
    __shared__ __align__(16) float a2[16][88];

    const int t = threadIdx.x;
    const bool q = (qflag[0] != 0);
    const int base = blockIdx.x * 16;
    const int og = t >> 3;
    const int ig = t & 7;

    float acc[4][2];
    #pragma unroll
    for (int j = 0; j < 4; ++j) { acc[j][0] = 0.0f; acc[j][1] = 0.0f; }

    for (int ch = 0; ch < 10; ++ch) {
        __syncthreads();
        for (int i = t; i < 1200; i += 256) {
            const int slot = i / 10, s = i % 10;
            const int orig = ((slot % 30) << 2) + (slot / 30);
            *reinterpret_cast<float4*>(&wt[slot][s * 4]) =
                *reinterpret_cast<const float4*>(w1 + orig * 400 + ch * 40 + s * 4);
        }
        for (int i = t; i < 160; i += 256) {
            const int imm = i / 10, s = i % 10;
            if (base + imm < B)
                *reinterpret_cast<float4*>(&a0c[imm][s * 4]) =
                    *reinterpret_cast<const float4*>(act + (size_t)(base + imm) * 400 + ch * 40 + s * 4);
        }
        __syncthreads();
        if (og < 30) {
            #pragma unroll
            for (int kk = 0; kk < 10; ++kk) {
                const float4 av0 = *reinterpret_cast<const float4*>(&a0c[2*ig][kk*4]);
                const float4 av1 = *reinterpret_cast<const float4*>(&a0c[2*ig+1][kk*4]);
                const float4 w0 = *reinterpret_cast<const float4*>(&wt[og][kk*4]);
                const float4 wv1 = *reinterpret_cast<const float4*>(&wt[30+og][kk*4]);
                const float4 wv2 = *reinterpret_cast<const float4*>(&wt[60+og][kk*4]);
                const float4 wv3 = *reinterpret_cast<const float4*>(&wt[90+og][kk*4]);
                acc[0][0]=fmaf(av0.x,w0.x,acc[0][0]);  acc[0][1]=fmaf(av1.x,w0.x,acc[0][1]);
                acc[1][0]=fmaf(av0.x,wv1.x,acc[1][0]); acc[1][1]=fmaf(av1.x,wv1.x,acc[1][1]);
                acc[2][0]=fmaf(av0.x,wv2.x,acc[2][0]); acc[2][1]=fmaf(av1.x,wv2.x,acc[2][1]);
                acc[3][0]=fmaf(av0.x,wv3.x,acc[3][0]); acc[3][1]=fmaf(av1.x,wv3.x,acc[3][1]);
                acc[0][0]=fmaf(av0.y,w0.y,acc[0][0]);  acc[0][1]=fmaf(av1.y,w0.y,acc[0][1]);
                acc[1][0]=fmaf(av0.y,wv1.y,acc[1][0]); acc[1][1]=fmaf(av1.y,wv1.y,acc[1][1]);
                acc[2][0]=fmaf(av0.y,wv2.y,acc[2][0]); acc[2][1]=fmaf(av1.y,wv2.y,acc[2][1]);
                acc[3][0]=fmaf(av0.y,wv3.y,acc[3][0]); acc[3][1]=fmaf(av1.y,wv3.y,acc[3][1]);
                acc[0][0]=fmaf(av0.z,w0.z,acc[0][0]);  acc[0][1]=fmaf(av1.z,w0.z,acc[0][1]);
                acc[1][0]=fmaf(av0.z,wv1.z,acc[1][0]); acc[1][1]=fmaf(av1.z,wv1.z,acc[1][1]);
                acc[2][0]=fmaf(av0.z,wv2.z,acc[2][0]); acc[2][1]=fmaf(av1.z,wv2.z,acc[2][1]);
                acc[3][0]=fmaf(av0.z,wv3.z,acc[3][0]); acc[3][1]=fmaf(av1.z,wv3.z,acc[3][1]);
                acc[0][0]=fmaf(av0.w,w0.w,acc[0][0]);  acc[0][1]=fmaf(av1.w,w0.w,acc[0][1]);
                acc[1][0]=fmaf(av0.w,wv1.w,acc[1][0]); acc[1][1]=fmaf(av1.w,wv1.w,acc[1][1]);
                acc[2][0]=fmaf(av0.w,wv2.w,acc[2][0]); acc[2][1]=fmaf(av1.w,wv2.w,acc[2][1]);
                acc[3][0]=fmaf(av0.w,wv3.w,acc[3][0]); acc[3][1]=fmaf(av1.w,wv3.w,acc[3][1]);
            }
        }
    }
    if (og < 30) {
        #pragma unroll
        for (int j = 0; j < 4; ++j) {
            const int o = og * 4 + j;
            #pragma unroll
            for (int i = 0; i < 2; ++i) {
                float v = acc[j][i] + b1[o];
                v = fmaxf(v, 0.0f);
                a1[2*ig + i][o] = q ? quant_comp_f(v) : v;
            }
        }
    }

    float bcc[4][2];
    #pragma unroll
    for (int j = 0; j < 4; ++j) { bcc[j][0] = 0.0f; bcc[j][1] = 0.0f; }

    for (int ch = 0; ch < 3; ++ch) {
        __syncthreads();
        for (int i = t; i < 840; i += 256) {
            const int slot = i / 10, s = i % 10;
            const int orig = ((slot % 21) << 2) + (slot / 21);
            *reinterpret_cast<float4*>(&wt[slot][s * 4]) =
                *reinterpret_cast<const float4*>(w2 + orig * 120 + ch * 40 + s * 4);
        }
        __syncthreads();
        if (og < 21) {
            #pragma unroll
            for (int kk = 0; kk < 10; ++kk) {
                const float4 av0 = *reinterpret_cast<const float4*>(&a1[2*ig][ch*40 + kk*4]);
                const float4 av1 = *reinterpret_cast<const float4*>(&a1[2*ig+1][ch*40 + kk*4]);
                const float4 w0 = *reinterpret_cast<const float4*>(&wt[og][kk*4]);
                const float4 wv1 = *reinterpret_cast<const float4*>(&wt[21+og][kk*4]);
                const float4 wv2 = *reinterpret_cast<const float4*>(&wt[42+og][kk*4]);
                const float4 wv3 = *reinterpret_cast<const float4*>(&wt[63+og][kk*4]);
                bcc[0][0]=fmaf(av0.x,w0.x,bcc[0][0]);  bcc[0][1]=fmaf(av1.x,w0.x,bcc[0][1]);
                bcc[1][0]=fmaf(av0.x,wv1.x,bcc[1][0]); bcc[1][1]=fmaf(av1.x,wv1.x,bcc[1][1]);
                bcc[2][0]=fmaf(av0.x,wv2.x,bcc[2][0]); bcc[2][1]=fmaf(av1.x,wv2.x,bcc[2][1]);
                bcc[3][0]=fmaf(av0.x,wv3.x,bcc[3][0]); bcc[3][1]=fmaf(av1.x,wv3.x,bcc[3][1]);
                bcc[0][0]=fmaf(av0.y,w0.y,bcc[0][0]);  bcc[0][1]=fmaf(av1.y,w0.y,bcc[0][1]);
                bcc[1][0]=fmaf(av0.y,wv1.y,bcc[1][0]); bcc[1][1]=fmaf(av1.y,wv1.y,bcc[1][1]);
                bcc[2][0]=fmaf(av0.y,wv2.y,bcc[2][0]); bcc[2][1]=fmaf(av1.y,wv2.y,bcc[2][1]);
                bcc[3][0]=fmaf(av0.y,wv3.y,bcc[3][0]); bcc[3][1]=fmaf(av1.y,wv3.y,bcc[3][1]);
                bcc[0][0]=fmaf(av0.z,w0.z,bcc[0][0]);  bcc[0][1]=fmaf(av1.z,w0.z,bcc[0][1]);
                bcc[1][0]=fmaf(av0.z,wv1.z,bcc[1][0]); bcc[1][1]=fmaf(av1.z,wv1.z,bcc[1][1]);
                bcc[2][0]=fmaf(av0.z,wv2.z,bcc[2][0]); bcc[2][1]=fmaf(av1.z,wv2.z,bcc[2][1]);
                bcc[3][0]=fmaf(av0.z,wv3.z,bcc[3][0]); bcc[3][1]=fmaf(av1.z,wv3.z,bcc[3][1]);
                bcc[0][0]=fmaf(av0.w,w0.w,bcc[0][0]);  bcc[0][1]=fmaf(av1.w,w0.w,bcc[0][1]);
                bcc[1][0]=fmaf(av0.w,wv1.w,bcc[1][0]); bcc[1][1]=fmaf(av1.w,wv1.w,bcc[1][1]);
                bcc[2][0]=fmaf(av0.w,wv2.w,bcc[2][0]); bcc[2][1]=fmaf(av1.w,wv2.w,bcc[2][1]);
                bcc[3][0]=fmaf(av0.w,wv3.w,bcc[3][0]); bcc[3][1]=fmaf(av1.w,wv3.w,bcc[3][1]);
            }
        }
    }
    if (og < 21) {
        #pragma unroll
        for (int j = 0; j < 4; ++j) {
            const int o = og * 4 + j;
            #pragma unroll
            for (int i = 0; i < 2; ++i) {
                float v = bcc[j][i] + b2[o];
                v = fmaxf(v, 0.0f);
                a2[2*ig + i][o] = q ? quant_comp_f(v) : v;
            }
        }
    }

    __syncthreads();
    {
        float* wtf = &wt[0][0];
        for (int i = t; i < 210; i += 256)
            reinterpret_cast<float4*>(wtf)[i] =
                reinterpret_cast<const float4*>(w3)[i];
    }
    __syncthreads();
    {
        const int grp = t >> 4;
        const int im = t & 15;
        const int o0 = 2 * grp;
        if (o0 < 10) {
            const float* wtf = &wt[0][0];
            float s0 = 0.0f, s1 = 0.0f;
            #pragma unroll
            for (int kk = 0; kk < 21; ++kk) {
                const float4 av = *reinterpret_cast<const float4*>(&a2[im][kk*4]);
                const float4 wa = *reinterpret_cast<const float4*>(&wtf[o0*84 + kk*4]);
                const float4 wb = *reinterpret_cast<const float4*>(&wtf[(o0+1)*84 + kk*4]);
                s0 = fmaf(av.x, wa.x, s0); s1 = fmaf(av.x, wb.x, s1);
                s0 = fmaf(av.y, wa.y, s0); s1 = fmaf(av.y, wb.y, s1);
                s0 = fmaf(av.z, wa.z, s0); s1 = fmaf(av.z, wb.z, s1);
                s0 = fmaf(av.w, wa.w, s0); s1 = fmaf(av.w, wb.w, s1);
            }
            if (base + im < B) {
                out[(size_t)(base + im) * 10 + o0]     = s0 + b3[o0];
                out[(size_t)(base + im) * 10 + o0 + 1] = s1 + b3[o0 + 1];
            }
        }
    }
}

extern "C" void kernel_launch(void* const* d_in, const int* in_sizes, int n_in,
                              void* d_out, int out_size, void* d_ws, size_t ws_size,
                              hipStream_t stream) {
    const float* x     = (const float*)d_in[0];
    const float* c1w   = (const float*)d_in[1];
    const float* c1b   = (const float*)d_in[2];
    const float* c2w   = (const float*)d_in[3];
    const float* c2b   = (const float*)d_in[4];
    const float* fc1w  = (const float*)d_in[5];
    const float* fc1b  = (const float*)d_in[6];
    const float* fc2w  = (const float*)d_in[7];
    const float* fc2b  = (const float*)d_in[8];
    const float* fc3w  = (const float*)d_in[9];
    const float* fc3b  = (const float*)d_in[10];
    const int*   qflag = (const int*)d_in[11];
    float* out = (float*)d_out;

    const int B = in_sizes[0] / 784;
    float* act = (float*)d_ws;  // [B,400]

    conv_fused_kernel<<<B, 192, 0, stream>>>(x, c1w, c1b, c2w, c2b, qflag, act);

    const int nblk = (B + 15) / 16;
    fc_fused_kernel<<<nblk, 256, 0, stream>>>(act, fc1w, fc1b, fc2w, fc2b,
                                              fc3w, fc3b, qflag, out, B);
}